// Round 6
// baseline (1456.865 us; speedup 1.0000x reference)
//
#include <hip/hip_runtime.h>

// Problem constants (fixed by setup_inputs)
#define BB 4
#define Q 75
#define WAY 5
#define HW 100
#define D 640
#define M 500          // shot*HW
#define QROWS 7500     // Q*HW
#define NDQ 30000      // BB*QROWS query descriptors

// ws layout: floats at low offsets, pre-split B arrays at byte offsets.
// TOTAL ws ask: ~27.3 MB (known-good from R4/R5).
#define WS_QINV 0
#define WS_SINV 30000
#define WS_QMEAN 40000     // BB*Q*D = 192000
#define WS_PROTO 232000    // BB*WAY*D = 12800
#define WS_FEAT 244800     // BB*Q*10 = 3000
#define WS_BH_BYTE 1048576u               // 20*32*20*1024 = 13107200 B
#define WS_BL_BYTE (1048576u + 13107200u)

using short8  = __attribute__((ext_vector_type(8))) short;
using short4v = __attribute__((ext_vector_type(4))) short;
using float4v = __attribute__((ext_vector_type(4))) float;

#define GLOBAL_LOAD_LDS16(g, l)                                                   \
    __builtin_amdgcn_global_load_lds(                                             \
        (const __attribute__((address_space(1))) unsigned int*)(g),               \
        (__attribute__((address_space(3))) unsigned int*)(l), 16, 0, 0)

__device__ __forceinline__ void split1(float v, unsigned short& h, unsigned short& l) {
    unsigned u = __float_as_uint(v);
    unsigned short hu = (unsigned short)(u >> 16);          // truncate to bf16
    float hf = __uint_as_float(u & 0xffff0000u);
    float lo = v - hf;                                       // exact residual
    unsigned short lu = (unsigned short)(__float_as_uint(lo) >> 16);
    h = hu; l = lu;
}

__device__ __forceinline__ void split_store(float4 v, float s, short* dh, short* dl) {
    unsigned short h0,h1,h2,h3,l0,l1,l2,l3;
    split1(v.x * s, h0, l0); split1(v.y * s, h1, l1);
    split1(v.z * s, h2, l2); split1(v.w * s, h3, l3);
    short4v hv, lv;
    hv[0]=(short)h0; hv[1]=(short)h1; hv[2]=(short)h2; hv[3]=(short)h3;
    lv[0]=(short)l0; lv[1]=(short)l1; lv[2]=(short)l2; lv[3]=(short)l3;
    *(short4v*)dh = hv;
    *(short4v*)dl = lv;
}

// in-register split of 8 scaled elements into bf16 hi/lo fragments
__device__ __forceinline__ void split8(float4 a0, float4 a1, float s, short8& h8, short8& l8) {
    unsigned short h, l;
    split1(a0.x * s, h, l); h8[0] = (short)h; l8[0] = (short)l;
    split1(a0.y * s, h, l); h8[1] = (short)h; l8[1] = (short)l;
    split1(a0.z * s, h, l); h8[2] = (short)h; l8[2] = (short)l;
    split1(a0.w * s, h, l); h8[3] = (short)h; l8[3] = (short)l;
    split1(a1.x * s, h, l); h8[4] = (short)h; l8[4] = (short)l;
    split1(a1.y * s, h, l); h8[5] = (short)h; l8[5] = (short)l;
    split1(a1.z * s, h, l); h8[6] = (short)h; l8[6] = (short)l;
    split1(a1.w * s, h, l); h8[7] = (short)h; l8[7] = (short)l;
}

// ---------------- kernel 0: pre-split B (normalize + bf16 hi/lo, frag-order) ---
__global__ __launch_bounds__(256) void presplit_b(const float* __restrict__ xs,
                                                  float* __restrict__ ws) {
    __shared__ float partial[256];
    __shared__ float sinvS[16];
    __shared__ short Sh[16][648];
    __shared__ short Sl[16][648];
    int bw = blockIdx.x >> 5;      // 0..19
    int rf = blockIdx.x & 31;      // 0..31
    int tid = threadIdx.x;
    int rho = tid & 15;
    int kc  = tid >> 4;            // 0..15, covers k in [kc*40, kc*40+40)
    int m = rf * 16 + rho;
    bool valid = (m < M);
    const float* src = xs + ((size_t)bw * M + m) * D + kc * 40;

    float4 v[10];
    float ss = 0.f;
    #pragma unroll
    for (int i = 0; i < 10; ++i) {
        v[i] = valid ? *(const float4*)(src + i * 4) : make_float4(0.f,0.f,0.f,0.f);
        ss += v[i].x*v[i].x + v[i].y*v[i].y + v[i].z*v[i].z + v[i].w*v[i].w;
    }
    partial[tid] = ss;
    __syncthreads();
    if (tid < 16) {
        float sum = 0.f;
        #pragma unroll
        for (int k = 0; k < 16; ++k) sum += partial[k * 16 + tid];
        float inv = (sum > 0.f) ? rsqrtf(sum) : 0.f;
        sinvS[tid] = inv;
        int mm = rf * 16 + tid;
        if (mm < M) ws[WS_SINV + bw * M + mm] = inv;
    }
    __syncthreads();
    float s = sinvS[rho];
    #pragma unroll
    for (int i = 0; i < 10; ++i) {
        int k = kc * 40 + i * 4;
        split_store(v[i], s, &Sh[rho][k], &Sl[rho][k]);
    }
    __syncthreads();
    int lane = tid & 63, wvv = tid >> 6;
    int rs = lane & 15, kg = lane >> 4;
    char* wsb = (char*)ws;
    #pragma unroll
    for (int p = 0; p < 5; ++p) {
        int kt = wvv * 5 + p;
        short8 hv = *(const short8*)&Sh[rs][kt * 32 + kg * 8];
        short8 lv = *(const short8*)&Sl[rs][kt * 32 + kg * 8];
        size_t fo = ((size_t)(bw * 32 + rf) * 20 + kt) * 1024 + lane * 16;
        *(short8*)(wsb + WS_BH_BYTE + fo) = hv;
        *(short8*)(wsb + WS_BL_BYTE + fo) = lv;
    }
}

// ---------------- kernel 1: inverse L2 norms of query descriptors --------------
__global__ void norms_kernel(const float* __restrict__ xq, float* __restrict__ ws) {
    int wid  = (int)((blockIdx.x * blockDim.x + threadIdx.x) >> 6);
    int lane = threadIdx.x & 63;
    if (wid >= NDQ) return;
    const float* p = xq + (size_t)wid * D;
    float s = 0.f;
    #pragma unroll
    for (int j = 0; j < D; j += 64) { float v = p[j + lane]; s += v * v; }
    for (int off = 32; off; off >>= 1) s += __shfl_down(s, off);
    if (lane == 0) ws[WS_QINV + wid] = rsqrtf(s);
}

// ---------------- kernel 2: query_mean (over HW) and proto (over shot*HW) ------
__global__ void means_kernel(const float* __restrict__ xq, const float* __restrict__ xs,
                             float* __restrict__ ws) {
    __shared__ float inv[M];
    int bid = blockIdx.x;
    if (bid < BB * Q) {
        for (int i = threadIdx.x; i < HW; i += blockDim.x) inv[i] = ws[WS_QINV + bid * HW + i];
        __syncthreads();
        const float* base = xq + (size_t)bid * HW * D;
        for (int d = threadIdx.x; d < D; d += blockDim.x) {
            float s = 0.f;
            for (int h = 0; h < HW; ++h) s += base[(size_t)h * D + d] * inv[h];
            ws[WS_QMEAN + bid * D + d] = s * (1.f / HW);
        }
    } else {
        int bw = bid - BB * Q; // 0..19
        for (int i = threadIdx.x; i < M; i += blockDim.x) inv[i] = ws[WS_SINV + bw * M + i];
        __syncthreads();
        const float* base = xs + (size_t)bw * M * D;
        for (int d = threadIdx.x; d < D; d += blockDim.x) {
            float s = 0.f;
            for (int m = 0; m < M; ++m) s += base[(size_t)m * D + d] * inv[m];
            ws[WS_PROTO + bw * D + d] = s * (1.f / M);
        }
    }
}

// ---------------- kernel 3: cosine-prototype logits + zero-init sim slots ------
__global__ void cos_kernel(float* __restrict__ ws) {
    int idx  = (int)((blockIdx.x * blockDim.x + threadIdx.x) >> 6);
    int lane = threadIdx.x & 63;
    if (idx >= BB * Q * WAY) return;
    int w = idx % WAY; int bq = idx / WAY; int b = bq / Q;
    const float* qm = ws + WS_QMEAN + bq * D;
    const float* pr = ws + WS_PROTO + (b * WAY + w) * D;
    float s = 0.f;
    #pragma unroll
    for (int j = 0; j < D; j += 64) s += qm[j + lane] * pr[j + lane];
    for (int off = 32; off; off >>= 1) s += __shfl_down(s, off);
    if (lane == 0) {
        ws[WS_FEAT + bq * 10 + w]     = s;
        ws[WS_FEAT + bq * 10 + 5 + w] = 0.f;
    }
}

// ---------------- kernel 4: small-block MFMA split-bf16 GEMM + top-5 -----------
// Block: 64 rows x M, 128 threads (2 waves), 4 col-chunks of 128.
// Wave wv owns rows 32wv..32wv+31 (2 row-frags), all 128 chunk cols: acc 2x8.
// B: LDS dbuf via global_load_lds from pre-split frag-order ws (shared by waves).
// A: fp32 register-direct + in-register split (no duplication, 4x1 row split).
// 4 blocks/CU resident (34 KB LDS, <=256 regs/wave) = 4 barrier domains.
#define BM6 64
#define NRT6 118      // ceil(7500/64)
#define CST 65

__global__ __launch_bounds__(128, 2) void dn4_kernel(const float* __restrict__ xq,
                                                     const float* __restrict__ ws_ro,
                                                     float* __restrict__ ws) {
    __shared__ __align__(16) char smem[34816];
    float* Cs  = (float*)smem;                 // 64*65*4 = 16640 B (unions buf0)
    float* Aux = (float*)(smem + 32768);       // 64*8*4 = 2048 B

    // XCD-grouping swizzle: 2360 = 8 * 295 exactly.
    int xb = blockIdx.x & 7, jb = blockIdx.x >> 3;
    int idx = xb * 295 + jb;
    int bw = idx / NRT6; int rt = idx % NRT6;
    int w = bw % WAY;    int b  = bw / WAY;

    int tid  = threadIdx.x;      // 0..127
    int lane = tid & 63;
    int wv   = tid >> 6;         // wave 0/1
    int lfree = lane & 15;
    int lq    = lane >> 4;

    // A rows for this wave: 64*rt + 32*wv + 16*jj + lfree
    const float* aptr[2]; float qv[2];
    #pragma unroll
    for (int jj = 0; jj < 2; ++jj) {
        int grow = rt * BM6 + wv * 32 + jj * 16 + lfree;
        bool ok = grow < QROWS;
        aptr[jj] = xq + ((size_t)b * QROWS + (ok ? grow : 0)) * D + lq * 8;
        qv[jj]   = ok ? ws_ro[WS_QINV + b * QROWS + grow] : 0.f;
    }

    float t0=-1e30f,t1=-1e30f,t2=-1e30f,t3=-1e30f,t4=-1e30f;

    #pragma unroll 1
    for (int mc = 0; mc < 4; ++mc) {
        float4v acc[2][8];
        #pragma unroll
        for (int jj = 0; jj < 2; ++jj)
            #pragma unroll
            for (int ii = 0; ii < 8; ++ii) {
                acc[jj][ii][0]=0.f; acc[jj][ii][1]=0.f; acc[jj][ii][2]=0.f; acc[jj][ii][3]=0.f;
            }
        // per-mc B source base (this wave stages hi if wv==0, lo if wv==1)
        const char* bsrc = (const char*)ws_ro + (wv ? WS_BL_BYTE : WS_BH_BYTE)
                         + ((size_t)((bw * 32 + mc * 8) * 20)) * 1024 + (size_t)lane * 16;

        // LDS buffer layout per buf: cf*2048 + hl*1024 (+ lane*16 by HW)
        #define STAGE_B(nbuf, kt) do {                                             \
            _Pragma("unroll")                                                      \
            for (int cf = 0; cf < 8; ++cf)                                         \
                GLOBAL_LOAD_LDS16(bsrc + (cf * 20 + (kt)) * 1024,                  \
                                  smem + (nbuf) * 16384 + cf * 2048 + wv * 1024);  \
        } while (0)
        #define LOAD_A(dst, kt) do {                                               \
            _Pragma("unroll")                                                      \
            for (int jj = 0; jj < 2; ++jj) {                                       \
                const float* p = aptr[jj] + (kt) * 32;                             \
                dst[jj][0] = *(const float4*)p;                                    \
                dst[jj][1] = *(const float4*)(p + 4);                              \
            }                                                                      \
        } while (0)
        #define COMPUTE(nbuf, af) do {                                             \
            short8 ahf[2], alf[2];                                                 \
            _Pragma("unroll")                                                      \
            for (int jj = 0; jj < 2; ++jj)                                         \
                split8(af[jj][0], af[jj][1], qv[jj], ahf[jj], alf[jj]);            \
            _Pragma("unroll")                                                      \
            for (int ii = 0; ii < 8; ++ii) {                                       \
                short8 bh = *(const short8*)(smem + (nbuf)*16384 + ii*2048 + lane*16);        \
                short8 bl = *(const short8*)(smem + (nbuf)*16384 + ii*2048 + 1024 + lane*16); \
                _Pragma("unroll")                                                  \
                for (int jj = 0; jj < 2; ++jj) {                                   \
                    acc[jj][ii] = __builtin_amdgcn_mfma_f32_16x16x32_bf16(ahf[jj], bh, acc[jj][ii], 0, 0, 0); \
                    acc[jj][ii] = __builtin_amdgcn_mfma_f32_16x16x32_bf16(ahf[jj], bl, acc[jj][ii], 0, 0, 0); \
                    acc[jj][ii] = __builtin_amdgcn_mfma_f32_16x16x32_bf16(alf[jj], bh, acc[jj][ii], 0, 0, 0); \
                }                                                                  \
            }                                                                      \
        } while (0)

        float4 afA[2][2], afB[2][2];
        // prologue: stage kt=0, preload A(0)
        STAGE_B(0, 0);
        LOAD_A(afA, 0);
        __syncthreads();

        #pragma unroll 1
        for (int kp = 0; kp < 10; ++kp) {
            int kt = kp * 2;
            STAGE_B(1, kt + 1);          // DMA next, early
            LOAD_A(afB, kt + 1);         // A regs for next, early
            COMPUTE(0, afA);             // ~466 cyc of MFMA hides the above
            __syncthreads();
            if (kp < 9) {
                STAGE_B(0, kt + 2);
                LOAD_A(afA, kt + 2);
            }
            COMPUTE(1, afB);
            __syncthreads();
        }

        // ---- scan: 2 halves of 64 cols; 128 scanners (2 segs/row) + Aux merge
        #pragma unroll 1
        for (int h = 0; h < 2; ++h) {
            #pragma unroll
            for (int jj = 0; jj < 2; ++jj)
                #pragma unroll
                for (int iiL = 0; iiL < 4; ++iiL) {
                    int ii = h * 4 + iiL;
                    int rbase = wv * 32 + jj * 16 + lq * 4;
                    #pragma unroll
                    for (int rr = 0; rr < 4; ++rr)
                        Cs[(rbase + rr) * CST + iiL * 16 + lfree] = acc[jj][ii][rr];
                }
            __syncthreads();
            int row = tid & 63, seg = tid >> 6;
            int base = mc * 128 + h * 64 + seg * 32;
            int nv = M - base; if (nv > 32) nv = 32; if (nv < 0) nv = 0;
            float s0=-1e30f,s1=-1e30f,s2=-1e30f,s3=-1e30f,s4=-1e30f;
            for (int c = 0; c < nv; ++c) {
                float v = Cs[row * CST + seg * 32 + c];
                if (v > s4) {
                    s4 = v;
                    if (s4 > s3) { float t = s3; s3 = s4; s4 = t; }
                    if (s3 > s2) { float t = s2; s2 = s3; s3 = t; }
                    if (s2 > s1) { float t = s1; s1 = s2; s2 = t; }
                    if (s1 > s0) { float t = s0; s0 = s1; s1 = t; }
                }
            }
            if (seg == 1) {
                Aux[row*8+0]=s0; Aux[row*8+1]=s1; Aux[row*8+2]=s2;
                Aux[row*8+3]=s3; Aux[row*8+4]=s4;
            }
            __syncthreads();
            if (seg == 0) {
                float cand[10] = { s0,s1,s2,s3,s4,
                                   Aux[row*8+0],Aux[row*8+1],Aux[row*8+2],
                                   Aux[row*8+3],Aux[row*8+4] };
                #pragma unroll
                for (int i = 0; i < 10; ++i) {
                    float v = cand[i];
                    if (v > t4) {
                        t4 = v;
                        if (t4 > t3) { float t = t3; t3 = t4; t4 = t; }
                        if (t3 > t2) { float t = t2; t2 = t3; t3 = t; }
                        if (t2 > t1) { float t = t1; t1 = t2; t2 = t; }
                        if (t1 > t0) { float t = t0; t0 = t1; t1 = t; }
                    }
                }
            }
        }
        #undef STAGE_B
        #undef LOAD_A
        #undef COMPUTE
    }

    if (tid < BM6) {
        int grow = rt * BM6 + tid;
        if (grow < QROWS) {
            int q = grow / HW;
            atomicAdd(&ws[WS_FEAT + (b * Q + q) * 10 + 5 + w],
                      (t0 + t1 + t2 + t3 + t4) * (1.f / M));
        }
    }
}

// ---------------- kernel 5: BatchNorm (training stats over q) + dilated conv ---
__global__ void bn_conv_kernel(const float* __restrict__ gamma, const float* __restrict__ beta,
                               const float* __restrict__ convw, const float* __restrict__ wsr,
                               float* __restrict__ out) {
    __shared__ float mu[10], rstd[10];
    int b = blockIdx.x;
    const float* feat = wsr + WS_FEAT + b * Q * 10;
    int t = threadIdx.x;
    if (t < 10) {
        float s = 0.f;
        for (int q = 0; q < Q; ++q) s += feat[q * 10 + t];
        float m = s / Q;
        float ss = 0.f;
        for (int q = 0; q < Q; ++q) { float d = feat[q * 10 + t] - m; ss += d * d; }
        mu[t] = m;
        rstd[t] = rsqrtf(ss / Q + 1e-5f);
    }
    __syncthreads();
    if (t < Q * WAY) {
        int q = t / WAY, j = t % WAY;
        float bn0 = (feat[q * 10 + j]     - mu[j])     * rstd[j]     * gamma[j]     + beta[j];
        float bn1 = (feat[q * 10 + 5 + j] - mu[5 + j]) * rstd[5 + j] * gamma[5 + j] + beta[5 + j];
        out[(b * Q + q) * WAY + j] = convw[0] * bn0 + convw[1] * bn1;
    }
}

extern "C" void kernel_launch(void* const* d_in, const int* in_sizes, int n_in,
                              void* d_out, int out_size, void* d_ws, size_t ws_size,
                              hipStream_t stream) {
    const float* xq    = (const float*)d_in[0];
    const float* xs    = (const float*)d_in[1];
    const float* gamma = (const float*)d_in[2];
    const float* beta  = (const float*)d_in[3];
    const float* convw = (const float*)d_in[4];
    float* ws  = (float*)d_ws;
    float* out = (float*)d_out;

    presplit_b<<<20 * 32, 256, 0, stream>>>(xs, ws);            // sinv + frag-order B
    norms_kernel<<<(NDQ + 3) / 4, 256, 0, stream>>>(xq, ws);    // qinv
    means_kernel<<<BB * Q + BB * WAY, 256, 0, stream>>>(xq, xs, ws);
    cos_kernel<<<(BB * Q * WAY + 3) / 4, 256, 0, stream>>>(ws);
    dn4_kernel<<<8 * 295, 128, 0, stream>>>(xq, ws, ws);
    bn_conv_kernel<<<BB, 384, 0, stream>>>(gamma, beta, convw, ws, out);
}

// Round 7
// 710.894 us; speedup vs baseline: 2.0493x; 2.0493x over previous
//
#include <hip/hip_runtime.h>

// Problem constants (fixed by setup_inputs)
#define BB 4
#define Q 75
#define WAY 5
#define HW 100
#define D 640
#define M 500          // shot*HW
#define QROWS 7500     // Q*HW
#define NRF 472        // padded row-frags per b: 59 blocks * 8 (7552 rows)

// ws layout: floats at low offsets, pre-split frag-order arrays after.
// TOTAL ws ask: ~99.8 MB.
#define WS_QINV 0
#define WS_SINV 30000
#define WS_QMEAN 40000     // BB*Q*D = 192000
#define WS_PROTO 232000    // BB*WAY*D = 12800
#define WS_FEAT 244800     // BB*Q*10 = 3000
#define WS_BH_BYTE 1048576u                       // 20*32*20*1024 = 13107200
#define WS_BL_BYTE (1048576u + 13107200u)         // 14155776
#define WS_AH_BYTE (14155776u + 13107200u)        // 27262976; 4*472*20*1024 = 38666240
#define WS_AL_BYTE (27262976u + 38666240u)        // 65929216; end 104595456

using short8  = __attribute__((ext_vector_type(8))) short;
using short4v = __attribute__((ext_vector_type(4))) short;
using float4v = __attribute__((ext_vector_type(4))) float;

__device__ __forceinline__ void split1(float v, unsigned short& h, unsigned short& l) {
    unsigned u = __float_as_uint(v);
    unsigned short hu = (unsigned short)(u >> 16);          // truncate to bf16
    float hf = __uint_as_float(u & 0xffff0000u);
    float lo = v - hf;                                       // exact residual
    unsigned short lu = (unsigned short)(__float_as_uint(lo) >> 16);
    h = hu; l = lu;
}

__device__ __forceinline__ void split_store(float4 v, float s, short* dh, short* dl) {
    unsigned short h0,h1,h2,h3,l0,l1,l2,l3;
    split1(v.x * s, h0, l0); split1(v.y * s, h1, l1);
    split1(v.z * s, h2, l2); split1(v.w * s, h3, l3);
    short4v hv, lv;
    hv[0]=(short)h0; hv[1]=(short)h1; hv[2]=(short)h2; hv[3]=(short)h3;
    lv[0]=(short)l0; lv[1]=(short)l1; lv[2]=(short)l2; lv[3]=(short)l3;
    *(short4v*)dh = hv;
    *(short4v*)dl = lv;
}

// ---------------- kernel 0a: pre-split B (normalize + bf16 hi/lo, frag-order) --
// byte = ((bw*32+rf)*20 + kt)*1024 + lane*16 ; lane=kg*16+rho holds
// B[n=rf*16+rho][k=kt*32+kg*8+j].
__global__ __launch_bounds__(256) void presplit_b(const float* __restrict__ xs,
                                                  float* __restrict__ ws) {
    __shared__ float partial[256];
    __shared__ float sinvS[16];
    __shared__ short Sh[16][648];
    __shared__ short Sl[16][648];
    int bw = blockIdx.x >> 5;      // 0..19
    int rf = blockIdx.x & 31;      // 0..31
    int tid = threadIdx.x;
    int rho = tid & 15;
    int kc  = tid >> 4;            // 0..15, k in [kc*40, kc*40+40)
    int m = rf * 16 + rho;
    bool valid = (m < M);
    const float* src = xs + ((size_t)bw * M + (valid ? m : 0)) * D + kc * 40;

    float4 v[10];
    float ss = 0.f;
    #pragma unroll
    for (int i = 0; i < 10; ++i) {
        v[i] = valid ? *(const float4*)(src + i * 4) : make_float4(0.f,0.f,0.f,0.f);
        ss += v[i].x*v[i].x + v[i].y*v[i].y + v[i].z*v[i].z + v[i].w*v[i].w;
    }
    partial[tid] = ss;
    __syncthreads();
    if (tid < 16) {
        float sum = 0.f;
        #pragma unroll
        for (int k = 0; k < 16; ++k) sum += partial[k * 16 + tid];
        float inv = (sum > 0.f) ? rsqrtf(sum) : 0.f;
        sinvS[tid] = inv;
        int mm = rf * 16 + tid;
        if (mm < M) ws[WS_SINV + bw * M + mm] = inv;
    }
    __syncthreads();
    float s = sinvS[rho];
    #pragma unroll
    for (int i = 0; i < 10; ++i) {
        int k = kc * 40 + i * 4;
        split_store(v[i], s, &Sh[rho][k], &Sl[rho][k]);
    }
    __syncthreads();
    int lane = tid & 63, wvv = tid >> 6;
    int rs = lane & 15, kg = lane >> 4;
    char* wsb = (char*)ws;
    #pragma unroll
    for (int p = 0; p < 5; ++p) {
        int kt = wvv * 5 + p;
        short8 hv = *(const short8*)&Sh[rs][kt * 32 + kg * 8];
        short8 lv = *(const short8*)&Sl[rs][kt * 32 + kg * 8];
        size_t fo = ((size_t)(bw * 32 + rf) * 20 + kt) * 1024 + lane * 16;
        *(short8*)(wsb + WS_BH_BYTE + fo) = hv;
        *(short8*)(wsb + WS_BL_BYTE + fo) = lv;
    }
}

// ---------------- kernel 0b: pre-split A (qinv + bf16 hi/lo, frag-order) -------
// byte = ((b*472+rf)*20 + kt)*1024 + lane*16 ; same lane mapping as B.
__global__ __launch_bounds__(256) void presplit_a(const float* __restrict__ xq,
                                                  float* __restrict__ ws) {
    __shared__ float partial[256];
    __shared__ float qinvS[16];
    __shared__ short Sh[16][648];
    __shared__ short Sl[16][648];
    int b  = blockIdx.x / NRF;
    int rf = blockIdx.x % NRF;     // 0..471
    int tid = threadIdx.x;
    int rho = tid & 15;
    int kc  = tid >> 4;
    int r = rf * 16 + rho;
    bool valid = (r < QROWS);
    const float* src = xq + ((size_t)b * QROWS + (valid ? r : 0)) * D + kc * 40;

    float4 v[10];
    float ss = 0.f;
    #pragma unroll
    for (int i = 0; i < 10; ++i) {
        v[i] = valid ? *(const float4*)(src + i * 4) : make_float4(0.f,0.f,0.f,0.f);
        ss += v[i].x*v[i].x + v[i].y*v[i].y + v[i].z*v[i].z + v[i].w*v[i].w;
    }
    partial[tid] = ss;
    __syncthreads();
    if (tid < 16) {
        float sum = 0.f;
        #pragma unroll
        for (int k = 0; k < 16; ++k) sum += partial[k * 16 + tid];
        float inv = (sum > 0.f) ? rsqrtf(sum) : 0.f;
        qinvS[tid] = inv;
        int rr = rf * 16 + tid;
        if (rr < QROWS) ws[WS_QINV + b * QROWS + rr] = inv;
    }
    __syncthreads();
    float s = qinvS[rho];
    #pragma unroll
    for (int i = 0; i < 10; ++i) {
        int k = kc * 40 + i * 4;
        split_store(v[i], s, &Sh[rho][k], &Sl[rho][k]);
    }
    __syncthreads();
    int lane = tid & 63, wvv = tid >> 6;
    int rs = lane & 15, kg = lane >> 4;
    char* wsb = (char*)ws;
    #pragma unroll
    for (int p = 0; p < 5; ++p) {
        int kt = wvv * 5 + p;
        short8 hv = *(const short8*)&Sh[rs][kt * 32 + kg * 8];
        short8 lv = *(const short8*)&Sl[rs][kt * 32 + kg * 8];
        size_t fo = ((size_t)(b * NRF + rf) * 20 + kt) * 1024 + lane * 16;
        *(short8*)(wsb + WS_AH_BYTE + fo) = hv;
        *(short8*)(wsb + WS_AL_BYTE + fo) = lv;
    }
}

// ---------------- kernel 2: query_mean (over HW) and proto (over shot*HW) ------
__global__ void means_kernel(const float* __restrict__ xq, const float* __restrict__ xs,
                             float* __restrict__ ws) {
    __shared__ float inv[M];
    int bid = blockIdx.x;
    if (bid < BB * Q) {
        for (int i = threadIdx.x; i < HW; i += blockDim.x) inv[i] = ws[WS_QINV + bid * HW + i];
        __syncthreads();
        const float* base = xq + (size_t)bid * HW * D;
        for (int d = threadIdx.x; d < D; d += blockDim.x) {
            float s = 0.f;
            for (int h = 0; h < HW; ++h) s += base[(size_t)h * D + d] * inv[h];
            ws[WS_QMEAN + bid * D + d] = s * (1.f / HW);
        }
    } else {
        int bw = bid - BB * Q; // 0..19
        for (int i = threadIdx.x; i < M; i += blockDim.x) inv[i] = ws[WS_SINV + bw * M + i];
        __syncthreads();
        const float* base = xs + (size_t)bw * M * D;
        for (int d = threadIdx.x; d < D; d += blockDim.x) {
            float s = 0.f;
            for (int m = 0; m < M; ++m) s += base[(size_t)m * D + d] * inv[m];
            ws[WS_PROTO + bw * D + d] = s * (1.f / M);
        }
    }
}

// ---------------- kernel 3: cosine-prototype logits + zero-init sim slots ------
__global__ void cos_kernel(float* __restrict__ ws) {
    int idx  = (int)((blockIdx.x * blockDim.x + threadIdx.x) >> 6);
    int lane = threadIdx.x & 63;
    if (idx >= BB * Q * WAY) return;
    int w = idx % WAY; int bq = idx / WAY; int b = bq / Q;
    const float* qm = ws + WS_QMEAN + bq * D;
    const float* pr = ws + WS_PROTO + (b * WAY + w) * D;
    float s = 0.f;
    #pragma unroll
    for (int j = 0; j < D; j += 64) s += qm[j + lane] * pr[j + lane];
    for (int off = 32; off; off >>= 1) s += __shfl_down(s, off);
    if (lane == 0) {
        ws[WS_FEAT + bq * 10 + w]     = s;
        ws[WS_FEAT + bq * 10 + 5 + w] = 0.f;
    }
}

// ---------------- kernel 4: pure load+MFMA GEMM + streaming top-5 --------------
// 1180 blocks (59 rt x 20 bw), 256 threads, 4 waves 2x2 over a 128x128 chunk,
// mc = 0..3 chunks. K-loop: ONLY global loads (frag-order ws) + MFMA; no LDS,
// no barriers, branch-free 1-deep pipeline (cur/nxt register sets).
#define BM 128
#define NRT 59
#define NBLK 1180
#define CST 65

__global__ __launch_bounds__(256, 2) void dn4_kernel(const float* __restrict__ ws_ro,
                                                     float* __restrict__ ws) {
    __shared__ float Cs[BM * CST];

    int xb = blockIdx.x & 7, jb = blockIdx.x >> 3;
    int idx = xb * 148 + jb;            // same-bw blocks adjacent per XCD
    if (idx >= NBLK) return;
    int bw = idx / NRT; int rt = idx % NRT;
    int w = bw % WAY;   int b  = bw / WAY;

    int tid  = threadIdx.x;
    int lane = tid & 63;
    int wave = tid >> 6;
    int wr = wave >> 1, wc = wave & 1;
    int lfree = lane & 15;
    int lq    = lane >> 4;

    const char* base = (const char*)ws_ro;
    // A frag offsets (mc-invariant): frag jj -> rf = rt*8 + wr*4 + jj
    unsigned ah0[4], al0[4];
    #pragma unroll
    for (int jj = 0; jj < 4; ++jj) {
        unsigned fo = (unsigned)((b * NRF + rt * 8 + wr * 4 + jj) * 20) * 1024u
                    + (unsigned)(lane * 16);
        ah0[jj] = WS_AH_BYTE + fo;
        al0[jj] = WS_AL_BYTE + fo;
    }

    float t0=-1e30f,t1=-1e30f,t2=-1e30f,t3=-1e30f,t4=-1e30f;

    #pragma unroll 1
    for (int mc = 0; mc < 4; ++mc) {
        float4v acc[4][4];
        #pragma unroll
        for (int jj = 0; jj < 4; ++jj)
            #pragma unroll
            for (int ii = 0; ii < 4; ++ii) {
                acc[jj][ii][0]=0.f; acc[jj][ii][1]=0.f; acc[jj][ii][2]=0.f; acc[jj][ii][3]=0.f;
            }
        unsigned ah[4], al[4], bh[4], bl[4];
        #pragma unroll
        for (int f = 0; f < 4; ++f) {
            ah[f] = ah0[f]; al[f] = al0[f];
            unsigned fo = (unsigned)((bw * 32 + mc * 8 + wc * 4 + f) * 20) * 1024u
                        + (unsigned)(lane * 16);
            bh[f] = WS_BH_BYTE + fo;
            bl[f] = WS_BL_BYTE + fo;
        }

        #define LD4(dst, off, ko) {                                                \
            _Pragma("unroll")                                                      \
            for (int f = 0; f < 4; ++f)                                            \
                dst[f] = *(const short8*)(base + (size_t)(off[f] + (ko)));         \
        }
        #define COMP(AH, AL, BH, BL) {                                             \
            _Pragma("unroll")                                                      \
            for (int jj = 0; jj < 4; ++jj)                                         \
                _Pragma("unroll")                                                  \
                for (int ii = 0; ii < 4; ++ii) {                                   \
                    acc[jj][ii] = __builtin_amdgcn_mfma_f32_16x16x32_bf16(AH[jj], BH[ii], acc[jj][ii], 0, 0, 0); \
                    acc[jj][ii] = __builtin_amdgcn_mfma_f32_16x16x32_bf16(AH[jj], BL[ii], acc[jj][ii], 0, 0, 0); \
                    acc[jj][ii] = __builtin_amdgcn_mfma_f32_16x16x32_bf16(AL[jj], BH[ii], acc[jj][ii], 0, 0, 0); \
                }                                                                  \
        }

        short8 ahc[4], alc[4], bhc[4], blc[4];
        short8 ahn[4], aln[4], bhn[4], bln[4];
        LD4(ahc, ah, 0); LD4(alc, al, 0); LD4(bhc, bh, 0); LD4(blc, bl, 0);
        #pragma unroll 1
        for (int kp = 0; kp < 9; ++kp) {   // cur = kt 2kp; loads 2kp+1, 2kp+2
            LD4(ahn, ah, 1024); LD4(aln, al, 1024);
            LD4(bhn, bh, 1024); LD4(bln, bl, 1024);
            COMP(ahc, alc, bhc, blc);
            LD4(ahc, ah, 2048); LD4(alc, al, 2048);
            LD4(bhc, bh, 2048); LD4(blc, bl, 2048);
            COMP(ahn, aln, bhn, bln);
            #pragma unroll
            for (int f = 0; f < 4; ++f) {
                ah[f] += 2048; al[f] += 2048; bh[f] += 2048; bl[f] += 2048;
            }
        }
        // kt = 18 in cur; load kt = 19, compute both
        LD4(ahn, ah, 1024); LD4(aln, al, 1024);
        LD4(bhn, bh, 1024); LD4(bln, bl, 1024);
        COMP(ahc, alc, bhc, blc);
        COMP(ahn, aln, bhn, bln);
        #undef LD4
        #undef COMP

        // ---- scan: two 64-col halves (C/D: col=lane&15, row=lq*4+reg) ----
        #pragma unroll 1
        for (int ch = 0; ch < 2; ++ch) {
            if (wc == ch) {
                #pragma unroll
                for (int jj = 0; jj < 4; ++jj)
                    #pragma unroll
                    for (int ii = 0; ii < 4; ++ii) {
                        int rbase = 64 * wr + 16 * jj + lq * 4;
                        #pragma unroll
                        for (int rr = 0; rr < 4; ++rr)
                            Cs[(rbase + rr) * CST + 16 * ii + lfree] = acc[jj][ii][rr];
                    }
            }
            __syncthreads();
            int m0 = mc * 128 + ch * 64;
            int validc = M - m0; if (validc > 64) validc = 64;
            if (tid < BM && rt * BM + tid < QROWS) {
                for (int c = 0; c < validc; ++c) {
                    float v = Cs[tid * CST + c];
                    if (v > t4) {
                        t4 = v;
                        if (t4 > t3) { float t = t3; t3 = t4; t4 = t; }
                        if (t3 > t2) { float t = t2; t2 = t3; t3 = t; }
                        if (t2 > t1) { float t = t1; t1 = t2; t2 = t; }
                        if (t1 > t0) { float t = t0; t0 = t1; t1 = t; }
                    }
                }
            }
            __syncthreads();
        }
    }

    if (tid < BM) {
        int grow = rt * BM + tid;
        if (grow < QROWS) {
            int q = grow / HW;
            atomicAdd(&ws[WS_FEAT + (b * Q + q) * 10 + 5 + w],
                      (t0 + t1 + t2 + t3 + t4) * (1.f / M));
        }
    }
}

// ---------------- kernel 5: BatchNorm (training stats over q) + dilated conv ---
__global__ void bn_conv_kernel(const float* __restrict__ gamma, const float* __restrict__ beta,
                               const float* __restrict__ convw, const float* __restrict__ wsr,
                               float* __restrict__ out) {
    __shared__ float mu[10], rstd[10];
    int b = blockIdx.x;
    const float* feat = wsr + WS_FEAT + b * Q * 10;
    int t = threadIdx.x;
    if (t < 10) {
        float s = 0.f;
        for (int q = 0; q < Q; ++q) s += feat[q * 10 + t];
        float m = s / Q;
        float ss = 0.f;
        for (int q = 0; q < Q; ++q) { float d = feat[q * 10 + t] - m; ss += d * d; }
        mu[t] = m;
        rstd[t] = rsqrtf(ss / Q + 1e-5f);
    }
    __syncthreads();
    if (t < Q * WAY) {
        int q = t / WAY, j = t % WAY;
        float bn0 = (feat[q * 10 + j]     - mu[j])     * rstd[j]     * gamma[j]     + beta[j];
        float bn1 = (feat[q * 10 + 5 + j] - mu[5 + j]) * rstd[5 + j] * gamma[5 + j] + beta[5 + j];
        out[(b * Q + q) * WAY + j] = convw[0] * bn0 + convw[1] * bn1;
    }
}

extern "C" void kernel_launch(void* const* d_in, const int* in_sizes, int n_in,
                              void* d_out, int out_size, void* d_ws, size_t ws_size,
                              hipStream_t stream) {
    const float* xq    = (const float*)d_in[0];
    const float* xs    = (const float*)d_in[1];
    const float* gamma = (const float*)d_in[2];
    const float* beta  = (const float*)d_in[3];
    const float* convw = (const float*)d_in[4];
    float* ws  = (float*)d_ws;
    float* out = (float*)d_out;

    presplit_b<<<20 * 32, 256, 0, stream>>>(xs, ws);       // sinv + frag-order B
    presplit_a<<<BB * NRF, 256, 0, stream>>>(xq, ws);      // qinv + frag-order A
    means_kernel<<<BB * Q + BB * WAY, 256, 0, stream>>>(xq, xs, ws);
    cos_kernel<<<(BB * Q * WAY + 3) / 4, 256, 0, stream>>>(ws);
    dn4_kernel<<<8 * 148, 256, 0, stream>>>(ws, ws);
    bn_conv_kernel<<<BB, 384, 0, stream>>>(gamma, beta, convw, ws, out);
}